// Round 2
// baseline (535.959 us; speedup 1.0000x reference)
//
#include <hip/hip_runtime.h>
#include <stdint.h>

#define N_ROWS 4096
#define F_DIM  2048
#define B_DIM  2048
#define K_DIM  4096   // F (h part) + B (behavior part)

typedef __attribute__((ext_vector_type(8)))  __bf16 bf16x8;
typedef __attribute__((ext_vector_type(16))) float  f32x16;
typedef unsigned short u16;

__device__ __forceinline__ u16 f2bf(float x) {
  unsigned int u = __float_as_uint(x);
  u += 0x7fffu + ((u >> 16) & 1u);   // RNE
  return (u16)(u >> 16);
}

__device__ __forceinline__ void async_copy16(const void* g, void* l) {
  __builtin_amdgcn_global_load_lds(
      (const __attribute__((address_space(1))) void*)g,
      (__attribute__((address_space(3))) void*)l, 16, 0, 0);
}

__device__ __forceinline__ float sigmoid_f(float x) {
  return 1.0f / (1.0f + __expf(-x));
}
__device__ __forceinline__ float tanh_f(float x) {
  float e2 = __expf(2.0f * x);
  return 1.0f - 2.0f / (e2 + 1.0f);
}

__device__ __forceinline__ f32x16 mm(bf16x8 a, bf16x8 b, f32x16 c) {
  return __builtin_amdgcn_mfma_f32_32x32x16_bf16(a, b, c, 0, 0, 0);
}

// ---------------- pack_x: Xc[n][k] = bf16( k<F ? h0[n][k] : behavior[n][k-F] )
__global__ __launch_bounds__(256) void pack_x_kernel(
    const float* __restrict__ h0, const float* __restrict__ behavior,
    u16* __restrict__ Xc)
{
  int tid = blockIdx.x * 256 + threadIdx.x;  // one thread = 8 consecutive k
  int row = tid >> 9;                        // K_DIM/8 = 512 octets per row
  int k0  = (tid & 511) * 8;
  const float* src = (k0 < F_DIM) ? (h0 + (size_t)row * F_DIM + k0)
                                  : (behavior + (size_t)row * B_DIM + (k0 - F_DIM));
  const float4* s4 = (const float4*)src;
  float4 a = s4[0], b = s4[1];
  uint4 o;
  o.x = (unsigned)f2bf(a.x) | ((unsigned)f2bf(a.y) << 16);
  o.y = (unsigned)f2bf(a.z) | ((unsigned)f2bf(a.w) << 16);
  o.z = (unsigned)f2bf(b.x) | ((unsigned)f2bf(b.y) << 16);
  o.w = (unsigned)f2bf(b.z) | ((unsigned)f2bf(b.w) << 16);
  *(uint4*)(Xc + (size_t)tid * 8) = o;
}

// ---------------- pack_w v3: WT[g][f][k] = bf16( k<F ? W?_h[k][f] : W?_x[k-F][f] )
__global__ __launch_bounds__(256) void pack_w_kernel(
    const float* __restrict__ wi_h, const float* __restrict__ wi_x,
    const float* __restrict__ wf_h, const float* __restrict__ wf_x,
    const float* __restrict__ wg_h, const float* __restrict__ wg_x,
    const float* __restrict__ wo_h, const float* __restrict__ wo_x,
    u16* __restrict__ WT)
{
  __shared__ float tileT[32 * 65];  // tileT[f_local][k_local], pad 65
  int g = blockIdx.z;
  const float* Wh = (g == 0) ? wi_h : (g == 1) ? wf_h : (g == 2) ? wg_h : wo_h;
  const float* Wx = (g == 0) ? wi_x : (g == 1) ? wf_x : (g == 2) ? wg_x : wo_x;
  int fb = blockIdx.x * 32;   // feature tile base
  int kb = blockIdx.y * 64;   // k tile base (block-uniform h/x split: 64 | 2048)
  const float* W = (kb < F_DIM) ? Wh : Wx;
  int kofs = (kb < F_DIM) ? kb : (kb - F_DIM);

  int t  = threadIdx.x;
  int c4 = t & 7;          // float4 column within f-tile (8*4 = 32 f)
  int kr = t >> 3;         // 0..31
#pragma unroll
  for (int p = 0; p < 2; ++p) {
    int k_l = kr + p * 32;  // 0..63
    float4 v = *(const float4*)(W + (size_t)(kofs + k_l) * F_DIM + fb + c4 * 4);
    tileT[(c4 * 4 + 0) * 65 + k_l] = v.x;
    tileT[(c4 * 4 + 1) * 65 + k_l] = v.y;
    tileT[(c4 * 4 + 2) * 65 + k_l] = v.z;
    tileT[(c4 * 4 + 3) * 65 + k_l] = v.w;
  }
  __syncthreads();
  {
    int f_l = t >> 3;            // 0..31
    int k8  = (t & 7) * 8;       // 0..56
    const float* s = tileT + f_l * 65 + k8;
    uint4 o;
    o.x = (unsigned)f2bf(s[0]) | ((unsigned)f2bf(s[1]) << 16);
    o.y = (unsigned)f2bf(s[2]) | ((unsigned)f2bf(s[3]) << 16);
    o.z = (unsigned)f2bf(s[4]) | ((unsigned)f2bf(s[5]) << 16);
    o.w = (unsigned)f2bf(s[6]) | ((unsigned)f2bf(s[7]) << 16);
    *(uint4*)(WT + ((size_t)g * F_DIM + fb + f_l) * K_DIM + kb + k8) = o;
  }
}

// ---------------- fused 4-gate GEMM + LSTM epilogue (v4: T3+T4+T5 pipeline)
// Block: 512 thr = 8 waves. Output: 256 rows x 64 f x 4 gates (= 256x256 eff).
// Waves 4x2: rw = wv&3 -> rows 64rw..; fh = wv>>2 -> f-cols 32fh..
// K-tile BK=32, double-buffered LDS 2 x (A 16KB + B 16KB) = 64 KB static.
// Per iter: 2 phases x {ds_read 6 frags, stage 2 chunks, barrier, 8 MFMA, barrier}.
// vmcnt(2) at phase 0 (next tile stays in flight -> never drains in main loop).
// LDS slot swizzle: slot s of row r stored at s ^ ((r>>1)&3): 8-lane ds_read_b128
// groups cover all 32 banks exactly once (conflict-free).
__global__ __launch_bounds__(512, 2) void lstm_gemm_kernel(
    const u16* __restrict__ Xc, const u16* __restrict__ WT,
    const float* __restrict__ c0,
    const float* __restrict__ bi, const float* __restrict__ bff,
    const float* __restrict__ bg, const float* __restrict__ bo,
    float* __restrict__ out)
{
  __shared__ u16 Ls[32768];   // 64 KB: buf(32KB = A 16KB | B 16KB) x 2

  const int tid  = threadIdx.x;
  const int lane = tid & 63;
  const int wv   = tid >> 6;
  const int bm   = blockIdx.x;   // rows bm*256
  const int bn   = blockIdx.y;   // f-cols bn*64

  const int rw   = wv & 3;       // row quarter (64 rows)
  const int fh   = wv >> 2;      // f half (32 f)
  const int l31  = lane & 31;
  const int half = lane >> 5;
  const int swb  = (l31 >> 1) & 3;   // row-pair swizzle component

  // ---- staging descriptors: per thread 2 A-chunks + 2 B-chunks per K-tile.
  // A chunk c (0..1023): row r=c>>2, slot s=c&3, stored octet o = s^((r>>1)&3)
  // B chunk c (0..1023): gate g=c>>8, row rb=(c&255)>>2, slot sb=c&3, same swz
  const u16* aSrc[2];
  const u16* bSrc[2];
#pragma unroll
  for (int p = 0; p < 2; ++p) {
    int c = p * 512 + tid;
    int r = c >> 2, s = c & 3;
    int o = s ^ ((r >> 1) & 3);
    aSrc[p] = Xc + (size_t)(bm * 256 + r) * K_DIM + o * 8;
    int g = c >> 8, cc = c & 255;
    int rb = cc >> 2, sb2 = cc & 3;
    int ob = sb2 ^ ((rb >> 1) & 3);
    bSrc[p] = WT + ((size_t)g * F_DIM + bn * 64 + rb) * K_DIM + ob * 8;
  }
  const unsigned ub = (unsigned)(tid & ~63) * 16u;  // wave-uniform LDS byte ofs

  f32x16 acc[4][2];
#pragma unroll
  for (int g = 0; g < 4; ++g)
#pragma unroll
    for (int rh = 0; rh < 2; ++rh)
#pragma unroll
      for (int r = 0; r < 16; ++r) acc[g][rh][r] = 0.f;

  // ---- prologue: stage tile 0 into buf0 (4 loads/thread)
#pragma unroll
  for (int p = 0; p < 2; ++p) {
    async_copy16(aSrc[p], (char*)Ls + p * 8192 + ub);
    async_copy16(bSrc[p], (char*)Ls + 16384 + p * 8192 + ub);
  }
#pragma unroll
  for (int p = 0; p < 2; ++p) { aSrc[p] += 32; bSrc[p] += 32; }

  int cur = 0;
  for (int kt = 0; kt < 128; ++kt) {
    const int nb = cur ^ 1;
    char* LdsN = (char*)Ls + nb * 32768;   // next-tile buffer (bytes)
    const u16* Lb = Ls + cur * 16384;      // current buffer (elems)
    const u16* Ab0 = Lb + (rw * 64 +      l31) * 32;
    const u16* Ab1 = Lb + (rw * 64 + 32 + l31) * 32;
    const u16* Bb  = Lb + 8192 + (fh * 32 + l31) * 32;

    // ================= phase 0 (k-chunk 0) =================
    if (kt < 127) {
      async_copy16(aSrc[0], LdsN + ub);
      async_copy16(bSrc[0], LdsN + 16384 + ub);
      asm volatile("s_waitcnt vmcnt(2)" ::: "memory");  // tile kt fully landed
    } else {
      asm volatile("s_waitcnt vmcnt(0)" ::: "memory");
    }
    __builtin_amdgcn_s_barrier();
    {
      const int sw8 = (half ^ swb) * 8;   // oct = 0*2 + half
      bf16x8 af0 = *(const bf16x8*)(Ab0 + sw8);
      bf16x8 af1 = *(const bf16x8*)(Ab1 + sw8);
      bf16x8 bfr[4];
#pragma unroll
      for (int g = 0; g < 4; ++g)
        bfr[g] = *(const bf16x8*)(Bb + g * 2048 + sw8);
      __builtin_amdgcn_s_setprio(1);
#pragma unroll
      for (int g = 0; g < 4; ++g) {
        acc[g][0] = mm(af0, bfr[g], acc[g][0]);
        acc[g][1] = mm(af1, bfr[g], acc[g][1]);
      }
      __builtin_amdgcn_s_setprio(0);
    }
    __builtin_amdgcn_s_barrier();

    // ================= phase 1 (k-chunk 1) =================
    {
      const int sw8 = ((2 + half) ^ swb) * 8;   // oct = 1*2 + half
      bf16x8 af0 = *(const bf16x8*)(Ab0 + sw8);
      bf16x8 af1 = *(const bf16x8*)(Ab1 + sw8);
      bf16x8 bfr[4];
#pragma unroll
      for (int g = 0; g < 4; ++g)
        bfr[g] = *(const bf16x8*)(Bb + g * 2048 + sw8);
      if (kt < 127) {
        async_copy16(aSrc[1], LdsN + 8192 + ub);
        async_copy16(bSrc[1], LdsN + 16384 + 8192 + ub);
      }
      __builtin_amdgcn_s_barrier();
      __builtin_amdgcn_s_setprio(1);
#pragma unroll
      for (int g = 0; g < 4; ++g) {
        acc[g][0] = mm(af0, bfr[g], acc[g][0]);
        acc[g][1] = mm(af1, bfr[g], acc[g][1]);
      }
      __builtin_amdgcn_s_setprio(0);
    }
    // own ds_reads fully complete before allowing buffer recycle next iter
    asm volatile("s_waitcnt lgkmcnt(0)" ::: "memory");
    __builtin_amdgcn_s_barrier();

#pragma unroll
    for (int p = 0; p < 2; ++p) { aSrc[p] += 32; bSrc[p] += 32; }
    cur ^= 1;
  }

  // ---- epilogue: 32x32 C/D layout: col = lane&31, row = (r&3)+8*(r>>2)+4*half
  {
    int f = bn * 64 + fh * 32 + l31;
    float b0 = bi[f], b1 = bff[f], b2 = bg[f], b3 = bo[f];
#pragma unroll
    for (int rh = 0; rh < 2; ++rh) {
      int row_base = bm * 256 + rw * 64 + rh * 32 + 4 * half;
#pragma unroll
      for (int r = 0; r < 16; ++r) {
        int row = row_base + (r & 3) + 8 * (r >> 2);
        size_t idx = (size_t)row * F_DIM + f;
        float pi = acc[0][rh][r] + b0;
        float pf = acc[1][rh][r] + b1;
        float pg = acc[2][rh][r] + b2;
        float po = acc[3][rh][r] + b3;
        float iv = sigmoid_f(pi);
        float fv = sigmoid_f(pf);
        float gv = tanh_f(pg);
        float ov = sigmoid_f(po);
        float cv = fv * c0[idx] + iv * gv;
        out[idx] = ov * tanh_f(cv);
      }
    }
  }
}

extern "C" void kernel_launch(void* const* d_in, const int* in_sizes, int n_in,
                              void* d_out, int out_size, void* d_ws, size_t ws_size,
                              hipStream_t stream) {
  const float* behavior = (const float*)d_in[0];
  const float* h0       = (const float*)d_in[1];
  const float* c0       = (const float*)d_in[2];
  const float* Wi_h     = (const float*)d_in[3];
  const float* Wi_x     = (const float*)d_in[4];
  const float* bi       = (const float*)d_in[5];
  const float* Wf_h     = (const float*)d_in[6];
  const float* Wf_x     = (const float*)d_in[7];
  const float* bf       = (const float*)d_in[8];
  const float* Wg_h     = (const float*)d_in[9];
  const float* Wg_x     = (const float*)d_in[10];
  const float* bg       = (const float*)d_in[11];
  const float* Wo_h     = (const float*)d_in[12];
  const float* Wo_x     = (const float*)d_in[13];
  const float* bo       = (const float*)d_in[14];
  float* out = (float*)d_out;

  // workspace: Xc (32 MB bf16) + WT (64 MB bf16) = ~96 MiB
  u16* Xc = (u16*)d_ws;
  u16* WT = Xc + (size_t)N_ROWS * K_DIM;

  pack_x_kernel<<<dim3(N_ROWS * (K_DIM / 8) / 256), 256, 0, stream>>>(h0, behavior, Xc);
  pack_w_kernel<<<dim3(F_DIM / 32, K_DIM / 64, 4), 256, 0, stream>>>(
      Wi_h, Wi_x, Wf_h, Wf_x, Wg_h, Wg_x, Wo_h, Wo_x, WT);
  lstm_gemm_kernel<<<dim3(N_ROWS / 256, F_DIM / 64), 512, 0, stream>>>(
      Xc, WT, c0, bi, bf, bg, bo, out);
}

// Round 4
// 511.381 us; speedup vs baseline: 1.0481x; 1.0481x over previous
//
#include <hip/hip_runtime.h>
#include <stdint.h>

#define N_ROWS 4096
#define F_DIM  2048
#define B_DIM  2048
#define K_DIM  4096   // F (h part) + B (behavior part)

typedef __attribute__((ext_vector_type(8)))  __bf16 bf16x8;
typedef __attribute__((ext_vector_type(16))) float  f32x16;
typedef unsigned short u16;

__device__ __forceinline__ u16 f2bf(float x) {
  unsigned int u = __float_as_uint(x);
  u += 0x7fffu + ((u >> 16) & 1u);   // RNE
  return (u16)(u >> 16);
}

__device__ __forceinline__ void async_copy16(const void* g, void* l) {
  __builtin_amdgcn_global_load_lds(
      (const __attribute__((address_space(1))) void*)g,
      (__attribute__((address_space(3))) void*)l, 16, 0, 0);
}

__device__ __forceinline__ float sigmoid_f(float x) {
  return 1.0f / (1.0f + __expf(-x));
}
__device__ __forceinline__ float tanh_f(float x) {
  float e2 = __expf(2.0f * x);
  return 1.0f - 2.0f / (e2 + 1.0f);
}

__device__ __forceinline__ f32x16 mm(bf16x8 a, bf16x8 b, f32x16 c) {
  return __builtin_amdgcn_mfma_f32_32x32x16_bf16(a, b, c, 0, 0, 0);
}

// ---------------- pack_x: Xc[n][k] = bf16( k<F ? h0[n][k] : behavior[n][k-F] )
__global__ __launch_bounds__(256) void pack_x_kernel(
    const float* __restrict__ h0, const float* __restrict__ behavior,
    u16* __restrict__ Xc)
{
  int tid = blockIdx.x * 256 + threadIdx.x;  // one thread = 8 consecutive k
  int row = tid >> 9;                        // K_DIM/8 = 512 octets per row
  int k0  = (tid & 511) * 8;
  const float* src = (k0 < F_DIM) ? (h0 + (size_t)row * F_DIM + k0)
                                  : (behavior + (size_t)row * B_DIM + (k0 - F_DIM));
  const float4* s4 = (const float4*)src;
  float4 a = s4[0], b = s4[1];
  uint4 o;
  o.x = (unsigned)f2bf(a.x) | ((unsigned)f2bf(a.y) << 16);
  o.y = (unsigned)f2bf(a.z) | ((unsigned)f2bf(a.w) << 16);
  o.z = (unsigned)f2bf(b.x) | ((unsigned)f2bf(b.y) << 16);
  o.w = (unsigned)f2bf(b.z) | ((unsigned)f2bf(b.w) << 16);
  *(uint4*)(Xc + (size_t)tid * 8) = o;
}

// ---------------- pack_w v3: WT[g][f][k] = bf16( k<F ? W?_h[k][f] : W?_x[k-F][f] )
__global__ __launch_bounds__(256) void pack_w_kernel(
    const float* __restrict__ wi_h, const float* __restrict__ wi_x,
    const float* __restrict__ wf_h, const float* __restrict__ wf_x,
    const float* __restrict__ wg_h, const float* __restrict__ wg_x,
    const float* __restrict__ wo_h, const float* __restrict__ wo_x,
    u16* __restrict__ WT)
{
  __shared__ float tileT[32 * 65];  // tileT[f_local][k_local], pad 65
  int g = blockIdx.z;
  const float* Wh = (g == 0) ? wi_h : (g == 1) ? wf_h : (g == 2) ? wg_h : wo_h;
  const float* Wx = (g == 0) ? wi_x : (g == 1) ? wf_x : (g == 2) ? wg_x : wo_x;
  int fb = blockIdx.x * 32;   // feature tile base
  int kb = blockIdx.y * 64;   // k tile base (block-uniform h/x split: 64 | 2048)
  const float* W = (kb < F_DIM) ? Wh : Wx;
  int kofs = (kb < F_DIM) ? kb : (kb - F_DIM);

  int t  = threadIdx.x;
  int c4 = t & 7;          // float4 column within f-tile (8*4 = 32 f)
  int kr = t >> 3;         // 0..31
#pragma unroll
  for (int p = 0; p < 2; ++p) {
    int k_l = kr + p * 32;  // 0..63
    float4 v = *(const float4*)(W + (size_t)(kofs + k_l) * F_DIM + fb + c4 * 4);
    tileT[(c4 * 4 + 0) * 65 + k_l] = v.x;
    tileT[(c4 * 4 + 1) * 65 + k_l] = v.y;
    tileT[(c4 * 4 + 2) * 65 + k_l] = v.z;
    tileT[(c4 * 4 + 3) * 65 + k_l] = v.w;
  }
  __syncthreads();
  {
    int f_l = t >> 3;            // 0..31
    int k8  = (t & 7) * 8;       // 0..56
    const float* s = tileT + f_l * 65 + k8;
    uint4 o;
    o.x = (unsigned)f2bf(s[0]) | ((unsigned)f2bf(s[1]) << 16);
    o.y = (unsigned)f2bf(s[2]) | ((unsigned)f2bf(s[3]) << 16);
    o.z = (unsigned)f2bf(s[4]) | ((unsigned)f2bf(s[5]) << 16);
    o.w = (unsigned)f2bf(s[6]) | ((unsigned)f2bf(s[7]) << 16);
    *(uint4*)(WT + ((size_t)g * F_DIM + fb + f_l) * K_DIM + kb + k8) = o;
  }
}

// ---------------- fused 4-gate GEMM + LSTM epilogue (v5: m201-style fat pipeline)
// Block: 512 thr = 8 waves. Output: 256 rows x 64 f x 4 gates.
// Waves 4x2: rw = wv&3 -> 64-row quarter; fh = wv>>2 -> 32-f half.
// BK=64, double-buffered LDS: 2 x (A 32KB + B 32KB) = 128 KB (1 block/CU).
// Per iter (64 total): issue 8 next-tile loads -> vmcnt(8) [tile kt landed;
// 8 new loads stay in flight across the barrier - never drains in main loop]
// -> barrier -> 4 k-chunks x {6 ds_read_b128, 8 MFMA (setprio 1)} -> lgkm(0)
// -> barrier. Fat 32-MFMA regions (v3 rate) + counted vmcnt (T4) + dbuf.
// Swizzle: 128B rows = 8 octets, store octet o = s ^ (row&7); read XOR same:
// 8-lane b128 groups hit all 32 banks exactly once.
__global__ __launch_bounds__(512, 2) void lstm_gemm_kernel(
    const u16* __restrict__ Xc, const u16* __restrict__ WT,
    const float* __restrict__ c0,
    const float* __restrict__ bi, const float* __restrict__ bff,
    const float* __restrict__ bg, const float* __restrict__ bo,
    float* __restrict__ out)
{
  __shared__ u16 Ls[2 * 32768];   // 128 KB: 2 x (A 16384 elems | B 16384 elems)

  const int tid  = threadIdx.x;
  const int lane = tid & 63;
  const int wv   = tid >> 6;
  const int bm   = blockIdx.x;   // rows bm*256
  const int bn   = blockIdx.y;   // f-cols bn*64

  const int rw   = wv & 3;       // row quarter (64 rows)
  const int fh   = wv >> 2;      // f half (32 f)
  const int l31  = lane & 31;
  const int half = lane >> 5;
  const int sA   = l31 & 7;      // row&7 for every fragment row used below

  // ---- staging descriptors: 8 x 16B chunks/thread per K-tile (64KB total).
  // chunk id c = p*512+tid. p<4 -> A (c in [0,2048)): row r=c>>3, slot s=c&7,
  // stored octet o = s^(r&7). p>=4 -> B (c-2048): gate g, f-row rb, same swz.
  const u16* src[8];
#pragma unroll
  for (int p = 0; p < 8; ++p) {
    int c = p * 512 + tid;
    if (p < 4) {
      int r = c >> 3, s = c & 7;
      int o = s ^ (r & 7);
      src[p] = Xc + (size_t)(bm * 256 + r) * K_DIM + o * 8;
    } else {
      int cb = c - 2048;
      int g = cb >> 9, cc = cb & 511;
      int rb = cc >> 3, sb = cc & 7;
      int ob = sb ^ (rb & 7);
      src[p] = WT + ((size_t)g * F_DIM + bn * 64 + rb) * K_DIM + ob * 8;
    }
  }
  const unsigned ub = (unsigned)(tid & ~63) * 16u;  // wave-uniform LDS byte ofs

  f32x16 acc[4][2];
#pragma unroll
  for (int g = 0; g < 4; ++g)
#pragma unroll
    for (int rh = 0; rh < 2; ++rh)
#pragma unroll
      for (int r = 0; r < 16; ++r) acc[g][rh][r] = 0.f;

  // ---- prologue: stage tile 0 into buf0
#pragma unroll
  for (int p = 0; p < 8; ++p)
    async_copy16(src[p], (char*)Ls + p * 8192 + ub);
#pragma unroll
  for (int p = 0; p < 8; ++p) src[p] += 64;

  int cur = 0;
  for (int kt = 0; kt < 64; ++kt) {
    char* LdsN = (char*)Ls + (cur ^ 1) * 65536;  // next-tile buffer (bytes)
    const u16* Lb = Ls + cur * 32768;            // current buffer (elems)

    if (kt < 63) {
#pragma unroll
      for (int p = 0; p < 8; ++p)
        async_copy16(src[p], LdsN + p * 8192 + ub);
      // outstanding = 8 (tile kt) + 8 (tile kt+1); wait for tile kt only.
      asm volatile("s_waitcnt vmcnt(8)" ::: "memory");
    } else {
      asm volatile("s_waitcnt vmcnt(0)" ::: "memory");
    }
    __builtin_amdgcn_s_barrier();

    const u16* Arow0 = Lb + (rw * 64 +      l31) * 64;            // A row, BK=64
    const u16* Arow1 = Lb + (rw * 64 + 32 + l31) * 64;
    const u16* Bbase = Lb + 16384 + (fh * 32 + l31) * 64;         // B at 32KB

#pragma unroll
    for (int c = 0; c < 4; ++c) {   // four k-chunks of 16 within the 64-k tile
      const int sw8 = ((c * 2 + half) ^ sA) * 8;
      bf16x8 af0 = *(const bf16x8*)(Arow0 + sw8);
      bf16x8 af1 = *(const bf16x8*)(Arow1 + sw8);
      bf16x8 bfr[4];
#pragma unroll
      for (int g = 0; g < 4; ++g)
        bfr[g] = *(const bf16x8*)(Bbase + g * 4096 + sw8);
      __builtin_amdgcn_s_setprio(1);
#pragma unroll
      for (int g = 0; g < 4; ++g) {
        acc[g][0] = mm(af0, bfr[g], acc[g][0]);
        acc[g][1] = mm(af1, bfr[g], acc[g][1]);
      }
      __builtin_amdgcn_s_setprio(0);
    }

    // own ds_reads complete before next iter's DMA overwrites this buffer
    asm volatile("s_waitcnt lgkmcnt(0)" ::: "memory");
    __builtin_amdgcn_s_barrier();

#pragma unroll
    for (int p = 0; p < 8; ++p) src[p] += 64;
    cur ^= 1;
  }

  // ---- epilogue: 32x32 C/D layout: col = lane&31, row = (r&3)+8*(r>>2)+4*half
  {
    int f = bn * 64 + fh * 32 + l31;
    float b0 = bi[f], b1 = bff[f], b2 = bg[f], b3 = bo[f];
#pragma unroll
    for (int rh = 0; rh < 2; ++rh) {
      int row_base = bm * 256 + rw * 64 + rh * 32 + 4 * half;
#pragma unroll
      for (int r = 0; r < 16; ++r) {
        int row = row_base + (r & 3) + 8 * (r >> 2);
        size_t idx = (size_t)row * F_DIM + f;
        float pi = acc[0][rh][r] + b0;
        float pf = acc[1][rh][r] + b1;
        float pg = acc[2][rh][r] + b2;
        float po = acc[3][rh][r] + b3;
        float iv = sigmoid_f(pi);
        float fv = sigmoid_f(pf);
        float gv = tanh_f(pg);
        float ov = sigmoid_f(po);
        float cv = fv * c0[idx] + iv * gv;
        out[idx] = ov * tanh_f(cv);
      }
    }
  }
}

extern "C" void kernel_launch(void* const* d_in, const int* in_sizes, int n_in,
                              void* d_out, int out_size, void* d_ws, size_t ws_size,
                              hipStream_t stream) {
  const float* behavior = (const float*)d_in[0];
  const float* h0       = (const float*)d_in[1];
  const float* c0       = (const float*)d_in[2];
  const float* Wi_h     = (const float*)d_in[3];
  const float* Wi_x     = (const float*)d_in[4];
  const float* bi       = (const float*)d_in[5];
  const float* Wf_h     = (const float*)d_in[6];
  const float* Wf_x     = (const float*)d_in[7];
  const float* bf       = (const float*)d_in[8];
  const float* Wg_h     = (const float*)d_in[9];
  const float* Wg_x     = (const float*)d_in[10];
  const float* bg       = (const float*)d_in[11];
  const float* Wo_h     = (const float*)d_in[12];
  const float* Wo_x     = (const float*)d_in[13];
  const float* bo       = (const float*)d_in[14];
  float* out = (float*)d_out;

  // workspace: Xc (32 MB bf16) + WT (64 MB bf16) = ~96 MiB
  u16* Xc = (u16*)d_ws;
  u16* WT = Xc + (size_t)N_ROWS * K_DIM;

  pack_x_kernel<<<dim3(N_ROWS * (K_DIM / 8) / 256), 256, 0, stream>>>(h0, behavior, Xc);
  pack_w_kernel<<<dim3(F_DIM / 32, K_DIM / 64, 4), 256, 0, stream>>>(
      Wi_h, Wi_x, Wf_h, Wf_x, Wg_h, Wg_x, Wo_h, Wo_x, WT);
  lstm_gemm_kernel<<<dim3(N_ROWS / 256, F_DIM / 64), 512, 0, stream>>>(
      Xc, WT, c0, bi, bf, bg, bo, out);
}